// Round 5
// baseline (7026.833 us; speedup 1.0000x reference)
//
#include <hip/hip_runtime.h>
#include <stdint.h>

#define WG 256
#define G 8            // elements per thread -> 2048 per workgroup
#define NDIST 65536
#define NSTEPS 250

// Threefry-2x32, 20 rounds, exactly as jax/_src/prng.py.
#define TF_ROUND(r) { x0 += x1; x1 = (x1 << (r)) | (x1 >> (32 - (r))); x1 ^= x0; }

__device__ __forceinline__ uint2 threefry2x32(uint32_t ks0, uint32_t ks1, uint32_t ks2,
                                              uint32_t x0, uint32_t x1) {
  x0 += ks0; x1 += ks1;
  TF_ROUND(13) TF_ROUND(15) TF_ROUND(26) TF_ROUND(6)
  x0 += ks1; x1 += ks2 + 1u;
  TF_ROUND(17) TF_ROUND(29) TF_ROUND(16) TF_ROUND(24)
  x0 += ks2; x1 += ks0 + 2u;
  TF_ROUND(13) TF_ROUND(15) TF_ROUND(26) TF_ROUND(6)
  x0 += ks0; x1 += ks1 + 3u;
  TF_ROUND(17) TF_ROUND(29) TF_ROUND(16) TF_ROUND(24)
  x0 += ks1; x1 += ks2 + 4u;
  TF_ROUND(13) TF_ROUND(15) TF_ROUND(26) TF_ROUND(6)
  x0 += ks2; x1 += ks0 + 5u;
  return make_uint2(x0, x1);
}

// One workgroup = 2048-element chunk of one batch. 4096 blocks total.
// Static LDS only (2 KB keys). Gather values straight from global (L2-resident).
__global__ __launch_bounds__(WG, 1) void fwd_diff_kernel(
    const float* __restrict__ x_init,   // [8,1024,1024] fp32
    const float* __restrict__ dist,     // [8,65536] fp32
    float* __restrict__ out) {          // [8,1024,1024] fp32
  __shared__ uint32_t keys[2 * NSTEPS];

  const int tid   = threadIdx.x;
  const int batch = blockIdx.x >> 9;    // 512 WGs per batch
  const int chunk = blockIdx.x & 511;
  const uint32_t base = ((uint32_t)batch << 20) + ((uint32_t)chunk << 11);

  // PARTITIONABLE threefry semantics (jax >= 0.4.30 default), x64-enabled harness:
  // split(key(42), 250) foldlike: keys[s] = TF((0,42),(0,s)) (both outputs).
  // randint: k1,k2 = split(key_s,2) foldlike -> k2 = TF(key_s,(0,1)).
  // x64: randint dtype=int64 -> random_bits(k2, 64): word = (TF(k2,(0,p)).x0 << 32)
  //      | TF(k2,(0,p)).x1; span=65536 -> multiplier=0 -> idx = .x1 & 0xFFFF.
  if (tid < NSTEPS) {
    uint2 ks = threefry2x32(0u, 42u, 0x1BD11BDAu ^ 42u, 0u, (uint32_t)tid);
    uint2 k2 = threefry2x32(ks.x, ks.y, ks.x ^ ks.y ^ 0x1BD11BDAu, 0u, 1u);
    keys[2 * tid]     = k2.x;
    keys[2 * tid + 1] = k2.y;
  }
  __syncthreads();

  const float* __restrict__ row = dist + (size_t)batch * NDIST;

  uint32_t p[G];
  float acc[G];
#pragma unroll
  for (int j = 0; j < G; ++j) {
    p[j]   = base + (uint32_t)(j * WG) + (uint32_t)tid;
    acc[j] = x_init[p[j]];
  }

  const float Ac = 0.9899494936611665f;  // float32(sqrt(0.98))
  const float Bc = 0.1414213562373095f;  // float32(sqrt(0.02))

  for (int s = 0; s < NSTEPS; ++s) {
    uint32_t kx = keys[2 * s];
    uint32_t ky = keys[2 * s + 1];
    kx = (uint32_t)__builtin_amdgcn_readfirstlane((int)kx);
    ky = (uint32_t)__builtin_amdgcn_readfirstlane((int)ky);
    const uint32_t kz = kx ^ ky ^ 0x1BD11BDAu;
#pragma unroll
    for (int j = 0; j < G; ++j) {
      uint2 r = threefry2x32(kx, ky, kz, 0u, p[j]);
      uint32_t idx = r.y & 0xFFFFu;   // low 32 of 64-bit draw = .y; mod 2^16
      float sv = row[idx];
      acc[j] = fmaf(Ac, acc[j], Bc * sv);
    }
  }

#pragma unroll
  for (int j = 0; j < G; ++j) out[p[j]] = acc[j];
}

extern "C" void kernel_launch(void* const* d_in, const int* in_sizes, int n_in,
                              void* d_out, int out_size, void* d_ws, size_t ws_size,
                              hipStream_t stream) {
  // Defensive: identify inputs by element count (8388608 vs 524288).
  const float* x_init = (const float*)d_in[0];
  const float* dist   = (const float*)d_in[1];
  if (n_in >= 2 && in_sizes[0] == 8 * NDIST) {  // swapped?
    x_init = (const float*)d_in[1];
    dist   = (const float*)d_in[0];
  }
  float* out = (float*)d_out;

  // 8 batches x 512 chunks; each WG covers 2048 elements (256 thr x G=8).
  fwd_diff_kernel<<<dim3(4096), dim3(WG), 0, stream>>>(x_init, dist, out);
}

// Round 8
// 4114.729 us; speedup vs baseline: 1.7077x; 1.7077x over previous
//
#include <hip/hip_runtime.h>
#include <hip/hip_fp16.h>
#include <stdint.h>

#define WG 512
#define G 8            // 4096 elements per workgroup -> 2048 WGs
#define NDIST 65536
#define NLDS 31744     // entries cached in LDS as fp16 (62 KB); rest from global/L2
#define NSTEPS 250

// Threefry-2x32, 20 rounds, exactly as jax/_src/prng.py.
#define TF_ROUND(r) { x0 += x1; x1 = (x1 << (r)) | (x1 >> (32 - (r))); x1 ^= x0; }

__device__ __forceinline__ uint2 threefry2x32(uint32_t ks0, uint32_t ks1, uint32_t ks2,
                                              uint32_t x0, uint32_t x1) {
  x0 += ks0; x1 += ks1;
  TF_ROUND(13) TF_ROUND(15) TF_ROUND(26) TF_ROUND(6)
  x0 += ks1; x1 += ks2 + 1u;
  TF_ROUND(17) TF_ROUND(29) TF_ROUND(16) TF_ROUND(24)
  x0 += ks2; x1 += ks0 + 2u;
  TF_ROUND(13) TF_ROUND(15) TF_ROUND(26) TF_ROUND(6)
  x0 += ks0; x1 += ks1 + 3u;
  TF_ROUND(17) TF_ROUND(29) TF_ROUND(16) TF_ROUND(24)
  x0 += ks1; x1 += ks2 + 4u;
  TF_ROUND(13) TF_ROUND(15) TF_ROUND(26) TF_ROUND(6)
  x0 += ks2; x1 += ks0 + 5u;
  return make_uint2(x0, x1);
}

// PRNG stream verified in R5 (partitionable foldlike split, 64-bit draw):
// keys[s] = TF((0,42),(0,s)); k2 = TF(key_s,(0,1)); idx = TF(k2,(0,p)).y & 0xFFFF.
// Resubmit of R7 unchanged: container failed twice on infra, kernel is API-free
// (static LDS only, no host calls) and cannot plausibly kill the container.
__global__ __launch_bounds__(WG, 1) void fwd_diff_hyb(
    const float* __restrict__ x_init,   // [8,1024,1024] fp32
    const float* __restrict__ dist,     // [8,65536] fp32
    float* __restrict__ out) {          // [8,1024,1024] fp32
  __shared__ __half   tab[NLDS];        // 62 KB, Bc pre-folded fp16
  __shared__ uint32_t keys[2 * NSTEPS]; // 2 KB   (total 65488 B static LDS)

  const int tid   = threadIdx.x;
  const int batch = blockIdx.x >> 8;    // 256 WGs per batch
  const int chunk = blockIdx.x & 255;
  const uint32_t base = ((uint32_t)batch << 20) + ((uint32_t)chunk << 12);

  const float Ac = 0.9899494936611665f;  // float32(sqrt(0.98))
  const float Bc = 0.1414213562373095f;  // float32(sqrt(0.02))

  const float* __restrict__ row = dist + (size_t)batch * NDIST;

  // Stage first NLDS entries as Bc-scaled fp16 (RNE). NLDS % 4 == 0.
  const float4* src4 = reinterpret_cast<const float4*>(row);
  for (int i = tid; i < NLDS / 4; i += WG) {
    float4 v = src4[i];
    ushort4 h;
    h.x = __half_as_ushort(__float2half(Bc * v.x));
    h.y = __half_as_ushort(__float2half(Bc * v.y));
    h.z = __half_as_ushort(__float2half(Bc * v.z));
    h.w = __half_as_ushort(__float2half(Bc * v.w));
    *reinterpret_cast<ushort4*>(&tab[i * 4]) = h;
  }

  if (tid < NSTEPS) {
    uint2 ks = threefry2x32(0u, 42u, 0x1BD11BDAu ^ 42u, 0u, (uint32_t)tid);
    uint2 k2 = threefry2x32(ks.x, ks.y, ks.x ^ ks.y ^ 0x1BD11BDAu, 0u, 1u);
    keys[2 * tid]     = k2.x;
    keys[2 * tid + 1] = k2.y;
  }
  __syncthreads();

  uint32_t p[G];
  float acc[G];
#pragma unroll
  for (int j = 0; j < G; ++j) {
    p[j]   = base + (uint32_t)(j * WG) + (uint32_t)tid;
    acc[j] = x_init[p[j]];
  }

  for (int s = 0; s < NSTEPS; ++s) {
    uint32_t kx = keys[2 * s];
    uint32_t ky = keys[2 * s + 1];
    kx = (uint32_t)__builtin_amdgcn_readfirstlane((int)kx);
    ky = (uint32_t)__builtin_amdgcn_readfirstlane((int)ky);
    const uint32_t kz = kx ^ ky ^ 0x1BD11BDAu;
#pragma unroll
    for (int j = 0; j < G; ++j) {
      uint2 r = threefry2x32(kx, ky, kz, 0u, p[j]);
      uint32_t idx = r.y & 0xFFFFu;
      float sv;
      if (idx < NLDS) {
        sv = __half2float(tab[idx]);   // Bc already folded in
      } else {
        sv = Bc * row[idx];            // L2-resident fp32
      }
      acc[j] = fmaf(Ac, acc[j], sv);
    }
  }

#pragma unroll
  for (int j = 0; j < G; ++j) out[p[j]] = acc[j];
}

extern "C" void kernel_launch(void* const* d_in, const int* in_sizes, int n_in,
                              void* d_out, int out_size, void* d_ws, size_t ws_size,
                              hipStream_t stream) {
  const float* x_init = (const float*)d_in[0];
  const float* dist   = (const float*)d_in[1];
  if (n_in >= 2 && in_sizes[0] == 8 * NDIST) {  // defensive swap check
    x_init = (const float*)d_in[1];
    dist   = (const float*)d_in[0];
  }
  float* out = (float*)d_out;

  // 8 batches x 256 chunks; each WG covers 4096 elements (512 thr x G=8).
  // No dynamic LDS, no host API calls -> graph-capture-safe.
  fwd_diff_hyb<<<dim3(2048), dim3(WG), 0, stream>>>(x_init, dist, out);
}

// Round 9
// 3556.215 us; speedup vs baseline: 1.9759x; 1.1571x over previous
//
#include <hip/hip_runtime.h>
#include <hip/hip_fp16.h>
#include <stdint.h>

#define NDIST 65536
#define NSTEPS 250

// Threefry-2x32, 20 rounds, exactly as jax/_src/prng.py.
#define TF_ROUND(r) { x0 += x1; x1 = (x1 << (r)) | (x1 >> (32 - (r))); x1 ^= x0; }

__device__ __forceinline__ uint2 threefry2x32(uint32_t ks0, uint32_t ks1, uint32_t ks2,
                                              uint32_t x0, uint32_t x1) {
  x0 += ks0; x1 += ks1;
  TF_ROUND(13) TF_ROUND(15) TF_ROUND(26) TF_ROUND(6)
  x0 += ks1; x1 += ks2 + 1u;
  TF_ROUND(17) TF_ROUND(29) TF_ROUND(16) TF_ROUND(24)
  x0 += ks2; x1 += ks0 + 2u;
  TF_ROUND(13) TF_ROUND(15) TF_ROUND(26) TF_ROUND(6)
  x0 += ks0; x1 += ks1 + 3u;
  TF_ROUND(17) TF_ROUND(29) TF_ROUND(16) TF_ROUND(24)
  x0 += ks1; x1 += ks2 + 4u;
  TF_ROUND(13) TF_ROUND(15) TF_ROUND(26) TF_ROUND(6)
  x0 += ks2; x1 += ks0 + 5u;
  return make_uint2(x0, x1);
}

// PRNG stream verified in R5 (partitionable foldlike split, 64-bit draw):
// keys[s] = TF((0,42),(0,s)); k2 = TF(key_s,(0,1)); idx = TF(k2,(0,p)).y & 0xFFFF.
__device__ __forceinline__ void init_keys(uint32_t* keys, int tid) {
  if (tid < NSTEPS) {
    uint2 ks = threefry2x32(0u, 42u, 0x1BD11BDAu ^ 42u, 0u, (uint32_t)tid);
    uint2 k2 = threefry2x32(ks.x, ks.y, ks.x ^ ks.y ^ 0x1BD11BDAu, 0u, 1u);
    keys[2 * tid]     = k2.x;
    keys[2 * tid + 1] = k2.y;
  }
}

// ---------- Fast path: FULL fp16 LDS table (Bc pre-folded), no dual path ----------
#define WGL 1024
#define GL  8   // 8192 elems per WG -> 1024 WGs

__global__ __launch_bounds__(WGL, 1) void fwd_diff_full(
    const float* __restrict__ x_init,   // [8,1024,1024] fp32
    const float* __restrict__ dist,     // [8,65536] fp32
    float* __restrict__ out) {          // [8,1024,1024] fp32
  extern __shared__ char smem[];
  __half*   tab  = reinterpret_cast<__half*>(smem);            // 128 KB
  uint32_t* keys = reinterpret_cast<uint32_t*>(smem + 131072); // 2 KB

  const int tid   = threadIdx.x;
  const int batch = blockIdx.x >> 7;    // 128 WGs per batch
  const int chunk = blockIdx.x & 127;
  const uint32_t base = ((uint32_t)batch << 20) + ((uint32_t)chunk << 13);

  const float Ac = 0.9899494936611665f;  // float32(sqrt(0.98))
  const float Bc = 0.1414213562373095f;  // float32(sqrt(0.02))

  const float4* src = reinterpret_cast<const float4*>(dist + (size_t)batch * NDIST);
  for (int i = tid; i < NDIST / 4; i += WGL) {
    float4 v = src[i];
    ushort4 h;
    h.x = __half_as_ushort(__float2half(Bc * v.x));
    h.y = __half_as_ushort(__float2half(Bc * v.y));
    h.z = __half_as_ushort(__float2half(Bc * v.z));
    h.w = __half_as_ushort(__float2half(Bc * v.w));
    reinterpret_cast<ushort4*>(tab)[i] = h;
  }
  init_keys(keys, tid);
  __syncthreads();

  uint32_t p[GL];
  float acc[GL];
#pragma unroll
  for (int j = 0; j < GL; ++j) {
    p[j]   = base + (uint32_t)(j * WGL) + (uint32_t)tid;
    acc[j] = x_init[p[j]];
  }

  for (int s = 0; s < NSTEPS; ++s) {
    uint32_t kx = keys[2 * s];
    uint32_t ky = keys[2 * s + 1];
    kx = (uint32_t)__builtin_amdgcn_readfirstlane((int)kx);
    ky = (uint32_t)__builtin_amdgcn_readfirstlane((int)ky);
    const uint32_t kz = kx ^ ky ^ 0x1BD11BDAu;
#pragma unroll
    for (int j = 0; j < GL; ++j) {
      uint2 r = threefry2x32(kx, ky, kz, 0u, p[j]);
      uint32_t idx = r.y & 0xFFFFu;
      acc[j] = fmaf(Ac, acc[j], __half2float(tab[idx]));  // Bc folded into table
    }
  }

#pragma unroll
  for (int j = 0; j < GL; ++j) out[p[j]] = acc[j];
}

// ---------- Fallback: proven R8 hybrid (62 KB static LDS + global upper half) ----------
#define WGH 512
#define GH  8
#define NLDS 31744

__global__ __launch_bounds__(WGH, 1) void fwd_diff_hyb(
    const float* __restrict__ x_init,
    const float* __restrict__ dist,
    float* __restrict__ out) {
  __shared__ __half   tab[NLDS];
  __shared__ uint32_t keys[2 * NSTEPS];

  const int tid   = threadIdx.x;
  const int batch = blockIdx.x >> 8;
  const int chunk = blockIdx.x & 255;
  const uint32_t base = ((uint32_t)batch << 20) + ((uint32_t)chunk << 12);

  const float Ac = 0.9899494936611665f;
  const float Bc = 0.1414213562373095f;

  const float* __restrict__ row = dist + (size_t)batch * NDIST;

  const float4* src4 = reinterpret_cast<const float4*>(row);
  for (int i = tid; i < NLDS / 4; i += WGH) {
    float4 v = src4[i];
    ushort4 h;
    h.x = __half_as_ushort(__float2half(Bc * v.x));
    h.y = __half_as_ushort(__float2half(Bc * v.y));
    h.z = __half_as_ushort(__float2half(Bc * v.z));
    h.w = __half_as_ushort(__float2half(Bc * v.w));
    *reinterpret_cast<ushort4*>(&tab[i * 4]) = h;
  }
  init_keys(keys, tid);
  __syncthreads();

  uint32_t p[GH];
  float acc[GH];
#pragma unroll
  for (int j = 0; j < GH; ++j) {
    p[j]   = base + (uint32_t)(j * WGH) + (uint32_t)tid;
    acc[j] = x_init[p[j]];
  }

  for (int s = 0; s < NSTEPS; ++s) {
    uint32_t kx = keys[2 * s];
    uint32_t ky = keys[2 * s + 1];
    kx = (uint32_t)__builtin_amdgcn_readfirstlane((int)kx);
    ky = (uint32_t)__builtin_amdgcn_readfirstlane((int)ky);
    const uint32_t kz = kx ^ ky ^ 0x1BD11BDAu;
#pragma unroll
    for (int j = 0; j < GH; ++j) {
      uint2 r = threefry2x32(kx, ky, kz, 0u, p[j]);
      uint32_t idx = r.y & 0xFFFFu;
      float sv;
      if (idx < NLDS) sv = __half2float(tab[idx]);
      else            sv = Bc * row[idx];
      acc[j] = fmaf(Ac, acc[j], sv);
    }
  }

#pragma unroll
  for (int j = 0; j < GH; ++j) out[p[j]] = acc[j];
}

extern "C" void kernel_launch(void* const* d_in, const int* in_sizes, int n_in,
                              void* d_out, int out_size, void* d_ws, size_t ws_size,
                              hipStream_t stream) {
  const float* x_init = (const float*)d_in[0];
  const float* dist   = (const float*)d_in[1];
  if (n_in >= 2 && in_sizes[0] == 8 * NDIST) {  // defensive swap check
    x_init = (const float*)d_in[1];
    dist   = (const float*)d_in[0];
  }
  float* out = (float*)d_out;

  const int smem_bytes = 131072 + 2048;  // full fp16 table + step keys

  // Deterministic gating (same outcome every call -> graph-safe).
  hipError_t st = hipFuncSetAttribute(
      reinterpret_cast<const void*>(fwd_diff_full),
      hipFuncAttributeMaxDynamicSharedMemorySize, smem_bytes);
  int max_blocks = 0;
  if (st == hipSuccess) {
    st = hipOccupancyMaxActiveBlocksPerMultiprocessor(
        &max_blocks, reinterpret_cast<const void*>(fwd_diff_full), WGL, smem_bytes);
  }

  if (st == hipSuccess && max_blocks >= 1) {
    // 8 batches x 128 chunks; 8192 elems/WG (1024 thr x G=8). 1 WG/CU.
    fwd_diff_full<<<dim3(1024), dim3(WGL), smem_bytes, stream>>>(x_init, dist, out);
  } else {
    // Proven R8 path: 4.1 ms.
    fwd_diff_hyb<<<dim3(2048), dim3(WGH), 0, stream>>>(x_init, dist, out);
  }
}

// Round 10
// 3543.443 us; speedup vs baseline: 1.9831x; 1.0036x over previous
//
#include <hip/hip_runtime.h>
#include <hip/hip_fp16.h>
#include <stdint.h>

#define NDIST 65536
#define NSTEPS 250

#if __has_builtin(__builtin_rotateleft32)
#define ROTL(x, r) __builtin_rotateleft32((x), (r))
#else
#define ROTL(x, r) (((x) << (r)) | ((x) >> (32 - (r))))
#endif

// Threefry-2x32, 20 rounds, exactly as jax/_src/prng.py. ROTL -> v_alignbit.
#define TF_ROUND(r) { x0 += x1; x1 = ROTL(x1, r); x1 ^= x0; }

__device__ __forceinline__ uint2 threefry2x32(uint32_t ks0, uint32_t ks1, uint32_t ks2,
                                              uint32_t x0, uint32_t x1) {
  x0 += ks0; x1 += ks1;
  TF_ROUND(13) TF_ROUND(15) TF_ROUND(26) TF_ROUND(6)
  x0 += ks1; x1 += ks2 + 1u;
  TF_ROUND(17) TF_ROUND(29) TF_ROUND(16) TF_ROUND(24)
  x0 += ks2; x1 += ks0 + 2u;
  TF_ROUND(13) TF_ROUND(15) TF_ROUND(26) TF_ROUND(6)
  x0 += ks0; x1 += ks1 + 3u;
  TF_ROUND(17) TF_ROUND(29) TF_ROUND(16) TF_ROUND(24)
  x0 += ks1; x1 += ks2 + 4u;
  TF_ROUND(13) TF_ROUND(15) TF_ROUND(26) TF_ROUND(6)
  x0 += ks2; x1 += ks0 + 5u;
  return make_uint2(x0, x1);
}

// PRNG stream verified in R5 (partitionable foldlike split, 64-bit draw):
// keys[s] = TF((0,42),(0,s)); k2 = TF(key_s,(0,1)); idx = TF(k2,(0,p)).y & 0xFFFF.

// ---- Setup kernel: 250 step-key pairs -> d_ws (read back via s_load) ----
__global__ void keys_kernel(uint32_t* __restrict__ ks_out) {
  const int tid = threadIdx.x;
  if (tid < NSTEPS) {
    uint2 ks = threefry2x32(0u, 42u, 0x1BD11BDAu ^ 42u, 0u, (uint32_t)tid);
    uint2 k2 = threefry2x32(ks.x, ks.y, ks.x ^ ks.y ^ 0x1BD11BDAu, 0u, 1u);
    ks_out[2 * tid]     = k2.x;
    ks_out[2 * tid + 1] = k2.y;
  }
}

// ---- Fast path v2: full fp16 LDS table, global scalar keys, G=16 ----
#define WGL 1024
#define GL  16   // 16384 elems per WG -> 512 WGs (2 per CU)

__global__ __launch_bounds__(WGL, 1) void fwd_diff_v2(
    const float* __restrict__ x_init,   // [8,1024,1024] fp32
    const float* __restrict__ dist,     // [8,65536] fp32
    const uint32_t* __restrict__ keysg, // [2*250] step keys (uniform)
    float* __restrict__ out) {          // [8,1024,1024] fp32
  extern __shared__ __half tab[];       // 128 KB, Bc pre-folded fp16

  const int tid   = threadIdx.x;
  const int batch = blockIdx.x >> 6;    // 64 WGs per batch
  const int chunk = blockIdx.x & 63;
  const uint32_t base = ((uint32_t)batch << 20) + ((uint32_t)chunk << 14);

  const float Ac = 0.9899494936611665f;  // float32(sqrt(0.98))
  const float Bc = 0.1414213562373095f;  // float32(sqrt(0.02))

  const float4* src = reinterpret_cast<const float4*>(dist + (size_t)batch * NDIST);
  for (int i = tid; i < NDIST / 4; i += WGL) {
    float4 v = src[i];
    ushort4 h;
    h.x = __half_as_ushort(__float2half(Bc * v.x));
    h.y = __half_as_ushort(__float2half(Bc * v.y));
    h.z = __half_as_ushort(__float2half(Bc * v.z));
    h.w = __half_as_ushort(__float2half(Bc * v.w));
    reinterpret_cast<ushort4*>(tab)[i] = h;
  }
  __syncthreads();

  uint32_t p[GL];
  float acc[GL];
#pragma unroll
  for (int j = 0; j < GL; ++j) {
    p[j]   = base + (uint32_t)(j * WGL) + (uint32_t)tid;
    acc[j] = x_init[p[j]];
  }

  for (int s = 0; s < NSTEPS; ++s) {
    // Loop-uniform global reads -> s_load_dwordx2 (no LDS sync point).
    const uint32_t kx = keysg[2 * s];
    const uint32_t ky = keysg[2 * s + 1];
    const uint32_t kz = kx ^ ky ^ 0x1BD11BDAu;

    uint32_t idx[GL];
#pragma unroll
    for (int j = 0; j < GL; ++j) {
      uint2 r = threefry2x32(kx, ky, kz, 0u, p[j]);
      idx[j] = r.y & 0xFFFFu;
    }
    // Batch the 16 ds_read_u16 issues, then consume (single lgkm wait window).
#pragma unroll
    for (int j = 0; j < GL; ++j) {
      acc[j] = fmaf(Ac, acc[j], __half2float(tab[idx[j]]));  // Bc folded in table
    }
  }

#pragma unroll
  for (int j = 0; j < GL; ++j) out[p[j]] = acc[j];
}

// ---- Fallback: proven R9 kernel (keys in LDS), unchanged ----
#define GF9 8

__global__ __launch_bounds__(WGL, 1) void fwd_diff_full(
    const float* __restrict__ x_init,
    const float* __restrict__ dist,
    float* __restrict__ out) {
  extern __shared__ char smem[];
  __half*   tab9 = reinterpret_cast<__half*>(smem);            // 128 KB
  uint32_t* keys = reinterpret_cast<uint32_t*>(smem + 131072); // 2 KB

  const int tid   = threadIdx.x;
  const int batch = blockIdx.x >> 7;
  const int chunk = blockIdx.x & 127;
  const uint32_t base = ((uint32_t)batch << 20) + ((uint32_t)chunk << 13);

  const float Ac = 0.9899494936611665f;
  const float Bc = 0.1414213562373095f;

  const float4* src = reinterpret_cast<const float4*>(dist + (size_t)batch * NDIST);
  for (int i = tid; i < NDIST / 4; i += WGL) {
    float4 v = src[i];
    ushort4 h;
    h.x = __half_as_ushort(__float2half(Bc * v.x));
    h.y = __half_as_ushort(__float2half(Bc * v.y));
    h.z = __half_as_ushort(__float2half(Bc * v.z));
    h.w = __half_as_ushort(__float2half(Bc * v.w));
    reinterpret_cast<ushort4*>(tab9)[i] = h;
  }
  if (tid < NSTEPS) {
    uint2 ks = threefry2x32(0u, 42u, 0x1BD11BDAu ^ 42u, 0u, (uint32_t)tid);
    uint2 k2 = threefry2x32(ks.x, ks.y, ks.x ^ ks.y ^ 0x1BD11BDAu, 0u, 1u);
    keys[2 * tid]     = k2.x;
    keys[2 * tid + 1] = k2.y;
  }
  __syncthreads();

  uint32_t p[GF9];
  float acc[GF9];
#pragma unroll
  for (int j = 0; j < GF9; ++j) {
    p[j]   = base + (uint32_t)(j * WGL) + (uint32_t)tid;
    acc[j] = x_init[p[j]];
  }

  for (int s = 0; s < NSTEPS; ++s) {
    uint32_t kx = keys[2 * s];
    uint32_t ky = keys[2 * s + 1];
    kx = (uint32_t)__builtin_amdgcn_readfirstlane((int)kx);
    ky = (uint32_t)__builtin_amdgcn_readfirstlane((int)ky);
    const uint32_t kz = kx ^ ky ^ 0x1BD11BDAu;
#pragma unroll
    for (int j = 0; j < GF9; ++j) {
      uint2 r = threefry2x32(kx, ky, kz, 0u, p[j]);
      uint32_t idx = r.y & 0xFFFFu;
      acc[j] = fmaf(Ac, acc[j], __half2float(tab9[idx]));
    }
  }

#pragma unroll
  for (int j = 0; j < GF9; ++j) out[p[j]] = acc[j];
}

extern "C" void kernel_launch(void* const* d_in, const int* in_sizes, int n_in,
                              void* d_out, int out_size, void* d_ws, size_t ws_size,
                              hipStream_t stream) {
  const float* x_init = (const float*)d_in[0];
  const float* dist   = (const float*)d_in[1];
  if (n_in >= 2 && in_sizes[0] == 8 * NDIST) {  // defensive swap check
    x_init = (const float*)d_in[1];
    dist   = (const float*)d_in[0];
  }
  float* out = (float*)d_out;
  uint32_t* keysg = (uint32_t*)d_ws;   // 2 KB of scratch

  const int smem_v2 = 131072;          // table only

  hipError_t st = hipFuncSetAttribute(
      reinterpret_cast<const void*>(fwd_diff_v2),
      hipFuncAttributeMaxDynamicSharedMemorySize, smem_v2);
  int max_blocks = 0;
  if (st == hipSuccess) {
    st = hipOccupancyMaxActiveBlocksPerMultiprocessor(
        &max_blocks, reinterpret_cast<const void*>(fwd_diff_v2), WGL, smem_v2);
  }

  if (st == hipSuccess && max_blocks >= 1 && ws_size >= 2 * NSTEPS * sizeof(uint32_t)) {
    keys_kernel<<<dim3(1), dim3(256), 0, stream>>>(keysg);
    // 8 batches x 64 chunks; 16384 elems/WG (1024 thr x G=16). 2 WG/CU.
    fwd_diff_v2<<<dim3(512), dim3(WGL), smem_v2, stream>>>(x_init, dist, keysg, out);
  } else {
    const int smem_v1 = 131072 + 2048;
    (void)hipFuncSetAttribute(reinterpret_cast<const void*>(fwd_diff_full),
                              hipFuncAttributeMaxDynamicSharedMemorySize, smem_v1);
    // Proven R9 path: 3.56 ms.
    fwd_diff_full<<<dim3(1024), dim3(WGL), smem_v1, stream>>>(x_init, dist, out);
  }
}